// Round 2
// baseline (946.759 us; speedup 1.0000x reference)
//
#include <hip/hip_runtime.h>

typedef unsigned int uint32;
typedef unsigned short ushort16;

typedef __attribute__((ext_vector_type(8))) short bf16x8;
typedef __attribute__((ext_vector_type(4))) float f32x4;

#define NNODES 32768
#define DFEAT 384
#define KPAD1 320

__device__ __forceinline__ float bf2f(ushort16 u) {
  union { uint32 i; float f; } x; x.i = ((uint32)u) << 16; return x.f;
}
__device__ __forceinline__ float bflo(uint32 v) {
  union { uint32 i; float f; } x; x.i = v << 16; return x.f;
}
__device__ __forceinline__ float bfhi(uint32 v) {
  union { uint32 i; float f; } x; x.i = v & 0xffff0000u; return x.f;
}
__device__ __forceinline__ ushort16 f2bf(float f) {
  union { float f; uint32 i; } x; x.f = f;
  uint32 r = (x.i + 0x7fffu + ((x.i >> 16) & 1u)) >> 16;
  return (ushort16)r;
}

// ---------------- fused prep: convert_x + deg_count + sent_mean ------------
// blocks [0, 8192): convert x_nodes f32 [32768,300] -> bf16 [32768,320]
// blocks [8192, 8192+degB): deg_count atomics
// blocks [8192+degB, +3072): sent_mean partials (256-thread remap of 768)
__global__ __launch_bounds__(256) void prep_kernel(
    const float* __restrict__ X, ushort16* __restrict__ A0,
    const int* __restrict__ dst, int* __restrict__ cnt, int E, int degB,
    const float* __restrict__ last, const float* __restrict__ first,
    float* __restrict__ Hpart) {
  int bx = blockIdx.x;
  int tid = threadIdx.x;
  if (bx < 8192) {
    int row = bx * 4 + (tid >> 6);
    int lane = tid & 63;
    const float* xr = X + (size_t)row * 300;
    ushort16* ar = A0 + (size_t)row * KPAD1;
#pragma unroll
    for (int i = 0; i < 5; ++i) {
      int col = lane + i * 64;
      float v = (col < 300) ? xr[col] : 0.f;
      ar[col] = f2bf(v);
    }
  } else if (bx < 8192 + degB) {
    int e = (bx - 8192) * 256 + tid;
    if (e < E) atomicAdd(&cnt[dst[e]], 1);
  } else {
    int idx = bx - 8192 - degB;        // [0, 3072): es*1024 + sc*64 + b
    int b = idx & 63, sc = (idx >> 6) & 15, es = idx >> 10;
    int e = es * 256 + tid;
    int s0 = sc * 32;
    const float* pl = last + ((size_t)b * 512 + s0) * 768 + e;
    const float* pf = first + ((size_t)b * 512 + s0) * 768 + e;
    float a0 = 0.f, a1 = 0.f, a2 = 0.f, a3 = 0.f;
    for (int i = 0; i < 32; i += 4) {
      a0 += pl[(i + 0) * 768] + pf[(i + 0) * 768];
      a1 += pl[(i + 1) * 768] + pf[(i + 1) * 768];
      a2 += pl[(i + 2) * 768] + pf[(i + 2) * 768];
      a3 += pl[(i + 3) * 768] + pf[(i + 3) * 768];
    }
    Hpart[((size_t)sc * 64 + b) * 768 + e] = a0 + a1 + a2 + a3;
  }
}

// ---------------- scan (+ disq folded) --------------------------------------
__global__ void scan_kernel(const int* __restrict__ cnt, int* __restrict__ row_start,
                            int* __restrict__ cursor, float* __restrict__ disq) {
  __shared__ int buf[1024];
  int t = threadIdx.x;
  int base = t * 32;
  int s = 0;
  for (int i = 0; i < 32; ++i) {
    int c = cnt[base + i];
    s += c;
    disq[base + i] = rsqrtf((float)c + 1.0f);  // +1 self loop
  }
  buf[t] = s; __syncthreads();
  int x = s;
  for (int off = 1; off < 1024; off <<= 1) {
    int v = (t >= off) ? buf[t - off] : 0;
    __syncthreads();
    x += v; buf[t] = x;
    __syncthreads();
  }
  int run = x - s;
  for (int i = 0; i < 32; ++i) {
    row_start[base + i] = run; cursor[base + i] = run;
    run += cnt[base + i];
  }
  if (t == 1023) row_start[NNODES] = run;
}

// ---------------- scatter (+ hsent folded) ----------------------------------
__global__ __launch_bounds__(256) void scatter_kernel(
    const int* __restrict__ src, const int* __restrict__ dst,
    int* __restrict__ cursor, int* __restrict__ csr, int E, int degB,
    const float* __restrict__ Hpart, float* __restrict__ Hsent) {
  int bx = blockIdx.x, t = threadIdx.x;
  if (bx < degB) {
    int e = bx * 256 + t;
    if (e < E) {
      int d = dst[e];
      int pos = atomicAdd(&cursor[d], 1);
      csr[pos] = src[e];
    }
  } else {
    int idx = bx - degB;               // [0, 192): es*64 + b
    int b = idx & 63, es = idx >> 6;
    int e = es * 256 + t;
    float h = 0.f;
#pragma unroll
    for (int sc = 0; sc < 16; ++sc) h += Hpart[((size_t)sc * 64 + b) * 768 + e];
    Hsent[(size_t)b * 768 + e] = h * (0.5f / 512.f);
  }
}

// ---------------- weight transform with inline BN-affine from spread stats --
__global__ void xform_w_kernel(const float* __restrict__ W, const float* __restrict__ bias,
                               const float* __restrict__ stat, const float* __restrict__ g,
                               const float* __restrict__ bb, float invN,
                               ushort16* __restrict__ BT, float* __restrict__ bias_out,
                               int K, int Kpad, int Nw) {
  __shared__ float red[128];
  int n = blockIdx.x, t = threadIdx.x;
  float part = 0.f;
  for (int k = t; k < Kpad; k += 128) {
    ushort16 o = 0; float contrib = 0.f;
    if (k < K) {
      float ak = 1.f, shk = 0.f;
      if (stat) {
        float s = 0.f, q = 0.f;
        for (int i = 0; i < 8; ++i) { s += stat[k * 8 + i]; q += stat[(DFEAT + k) * 8 + i]; }
        float mean = s * invN, var = q * invN - mean * mean;
        ak = g[k] * rsqrtf(var + 1e-5f);
        shk = bb[k] - ak * mean;
      }
      float w = W[(size_t)k * Nw + n];
      o = f2bf(ak * w);
      contrib = shk * w;
    }
    BT[(size_t)n * Kpad + k] = o;
    part += contrib;
  }
  red[t] = part; __syncthreads();
  for (int off = 64; off > 0; off >>= 1) {
    if (t < off) red[t] += red[t + off];
    __syncthreads();
  }
  if (t == 0) bias_out[n] = (bias ? bias[n] : 0.f) + red[0];
}

// ---------------- MFMA bf16 GEMM with fused stats / row-scale ---------------
#define BM 128
#define BN 128
#define BKT 32
#define LDT 40  // BKT + 8 pad shorts

template <bool RELU, bool STATS, bool RSCALE>
__global__ __launch_bounds__(256) void gemm_bf16(
    const ushort16* __restrict__ A, int lda, const ushort16* __restrict__ BT, int ldb,
    const float* __restrict__ bias, const float* __restrict__ rowscale,
    ushort16* __restrict__ C, int Ntot, int K, float* __restrict__ stat) {
  __shared__ __attribute__((aligned(16))) ushort16 As[BM * LDT];
  __shared__ __attribute__((aligned(16))) ushort16 Bs[BN * LDT];
  __shared__ float ssum[BN], ssq[BN];
  int bm0 = blockIdx.x * BM, bn0 = blockIdx.y * BN;
  int tid = threadIdx.x;
  if (STATS) {
    if (tid < BN) { ssum[tid] = 0.f; ssq[tid] = 0.f; }
  }
  int lane = tid & 63, wave = tid >> 6;
  int wm = (wave & 1) * 64, wn = (wave >> 1) * 64;
  int l15 = lane & 15, quad = lane >> 4;

  f32x4 acc[4][4];
  for (int i = 0; i < 4; ++i)
    for (int j = 0; j < 4; ++j) acc[i][j] = (f32x4)0.f;

  for (int kk = 0; kk < K; kk += BKT) {
    __syncthreads();
    for (int i = 0; i < 2; ++i) {
      int chunk = tid + i * 256;
      int row = chunk >> 2, cc = chunk & 3;
      uint4 va = *(const uint4*)(A + (size_t)(bm0 + row) * lda + kk + cc * 8);
      *(uint4*)(&As[row * LDT + cc * 8]) = va;
      uint4 vb = *(const uint4*)(BT + (size_t)(bn0 + row) * ldb + kk + cc * 8);
      *(uint4*)(&Bs[row * LDT + cc * 8]) = vb;
    }
    __syncthreads();
    bf16x8 af[4], bfr[4];
    for (int mi = 0; mi < 4; ++mi)
      af[mi] = *(const bf16x8*)(&As[(wm + mi * 16 + l15) * LDT + quad * 8]);
    for (int ni = 0; ni < 4; ++ni)
      bfr[ni] = *(const bf16x8*)(&Bs[(wn + ni * 16 + l15) * LDT + quad * 8]);
    for (int mi = 0; mi < 4; ++mi)
      for (int ni = 0; ni < 4; ++ni)
        acc[mi][ni] = __builtin_amdgcn_mfma_f32_16x16x32_bf16(af[mi], bfr[ni], acc[mi][ni], 0, 0, 0);
  }
  for (int ni = 0; ni < 4; ++ni) {
    int coll = wn + ni * 16 + l15;
    int col = bn0 + coll;
    float bv = bias[col];
    float s = 0.f, q = 0.f;
    for (int mi = 0; mi < 4; ++mi) {
      for (int r = 0; r < 4; ++r) {
        int row = bm0 + wm + mi * 16 + quad * 4 + r;
        float v = acc[mi][ni][r] + bv;
        if (RELU) v = fmaxf(v, 0.f);
        if (RSCALE) v *= rowscale[row];
        C[(size_t)row * Ntot + col] = f2bf(v);
        if (STATS) { s += v; q += v * v; }
      }
    }
    if (STATS) { atomicAdd(&ssum[coll], s); atomicAdd(&ssq[coll], q); }
  }
  if (STATS) {
    __syncthreads();
    int sp = blockIdx.x & 7;
    if (tid < BN) {
      atomicAdd(&stat[(bn0 + tid) * 8 + sp], ssum[tid]);
      atomicAdd(&stat[(DFEAT + bn0 + tid) * 8 + sp], ssq[tid]);
    }
  }
}

// ---------------- chunked, XCD-affine GCN aggregation -----------------------
// Dual-edge uint2 inner loop: 16 lanes x 8B per edge, 2 edges per 32-lane half
// per step. Same 128B/edge granularity -> chunk slice stays 4MB (L2-resident).
// XWs rows prescaled by disq: RC[n] = relu(disq[n] * (XWs[n] + sum_s XWs[s]) + b)
__global__ void __launch_bounds__(256) aggregate_kernel(
    const uint32* __restrict__ XWs, const int* __restrict__ csr,
    const int* __restrict__ row_start, const float* __restrict__ disq,
    const float* __restrict__ bconv, uint32* __restrict__ RC2,
    float* __restrict__ stat) {
  int bx = blockIdx.x;
  int slot = bx & 7, g = bx >> 3;
  int chunk = slot < 6 ? slot : (slot == 6 ? 0 : 3);
  int noff = slot < 6 ? 0 : 16384;
  int ngrp = (slot == 0 || slot == 3 || slot >= 6) ? 512 : 1024;
  if (g >= ngrp) return;
  __shared__ float ssum[64], ssq[64];
  int tid = threadIdx.x;
  if (tid < 64) { ssum[tid] = 0.f; ssq[tid] = 0.f; }
  __syncthreads();
  int lane = tid & 63, wave = tid >> 6;
  int half = lane >> 5;          // edge-segment of the node's list
  int sub = (lane >> 4) & 1;     // which of the 2 edges in a dual step
  int ll = lane & 15;            // feature-pair owner (2 uint32 = 4 feats)
  int cl = lane & 31;            // edge-slot for idx load
  int hb = half << 5;
  int hsub = hb + sub;
  const uint2* XW2 = (const uint2*)XWs;  // row stride = 96 uint2
  int coff = chunk * 16 + ll;            // uint2 offset within row
  float4 bq = *(const float4*)(bconv + chunk * 64 + 4 * ll);
  float ls0 = 0.f, ls1 = 0.f, ls2 = 0.f, ls3 = 0.f;
  float lq0 = 0.f, lq1 = 0.f, lq2 = 0.f, lq3 = 0.f;
  int nodebase = noff + (g * 4 + wave) * 8;
  for (int ni = 0; ni < 8; ++ni) {
    int n = nodebase + ni;
    int beg = row_start[n], end = row_start[n + 1];
    int deg = end - beg;
    int len0 = (deg + 1) >> 1;  // half 0 gets the longer part
    int myBeg = beg + (half ? len0 : 0);
    int myLen = half ? (deg - len0) : len0;
    float a0, a1, a2, a3;
    if (lane < 16) {  // self term, added once
      uint2 v = XW2[(size_t)n * 96 + coff];
      a0 = bflo(v.x); a1 = bfhi(v.x); a2 = bflo(v.y); a3 = bfhi(v.y);
    } else { a0 = 0.f; a1 = 0.f; a2 = 0.f; a3 = 0.f; }
    for (int bb0 = 0; bb0 < len0; bb0 += 32) {
      int rem = myLen - bb0;
      int idx = (cl < rem) ? csr[myBeg + bb0 + cl] : -1;
      int jmax = min(32, len0 - bb0);          // uniform over wave
      int remMin = (deg - len0) - bb0;         // shorter half's remaining
      int nfast = min(jmax, max(remMin, 0)) & ~1;
      int jj = 0;
      for (; jj + 16 <= nfast; jj += 16) {     // 8 dual-steps, no masking
        uint2 v[8];
#pragma unroll
        for (int u = 0; u < 8; ++u) {
          int s = __shfl(idx, hsub + jj + 2 * u, 64);
          v[u] = XW2[(size_t)s * 96 + coff];
        }
#pragma unroll
        for (int u = 0; u < 8; ++u) {
          a0 += bflo(v[u].x); a1 += bfhi(v[u].x);
          a2 += bflo(v[u].y); a3 += bfhi(v[u].y);
        }
      }
      for (; jj + 2 <= nfast; jj += 2) {
        int s = __shfl(idx, hsub + jj, 64);
        uint2 v = XW2[(size_t)s * 96 + coff];
        a0 += bflo(v.x); a1 += bfhi(v.x); a2 += bflo(v.y); a3 += bfhi(v.y);
      }
      for (; jj < jmax; jj += 2) {             // masked tail (dual step)
        int e0 = jj + sub;
        int s = __shfl(idx, hb + (e0 & 31), 64);
        bool val = (e0 < jmax) && (s >= 0);
        int sa = val ? s : 0;
        uint32 m = val ? 0xffffffffu : 0u;
        uint2 v = XW2[(size_t)sa * 96 + coff];
        v.x &= m; v.y &= m;
        a0 += bflo(v.x); a1 += bfhi(v.x); a2 += bflo(v.y); a3 += bfhi(v.y);
      }
    }
    // combine sub pair, then halves
    a0 += __shfl_xor(a0, 16, 64); a1 += __shfl_xor(a1, 16, 64);
    a2 += __shfl_xor(a2, 16, 64); a3 += __shfl_xor(a3, 16, 64);
    a0 += __shfl_xor(a0, 32, 64); a1 += __shfl_xor(a1, 32, 64);
    a2 += __shfl_xor(a2, 32, 64); a3 += __shfl_xor(a3, 32, 64);
    if (lane < 16) {
      float din = disq[n];
      a0 = fmaxf(din * a0 + bq.x, 0.f);
      a1 = fmaxf(din * a1 + bq.y, 0.f);
      a2 = fmaxf(din * a2 + bq.z, 0.f);
      a3 = fmaxf(din * a3 + bq.w, 0.f);
      uint2 o;
      o.x = (uint32)f2bf(a0) | ((uint32)f2bf(a1) << 16);
      o.y = (uint32)f2bf(a2) | ((uint32)f2bf(a3) << 16);
      *(uint2*)&RC2[(size_t)n * 192 + chunk * 32 + 2 * ll] = o;
      ls0 += a0; lq0 += a0 * a0; ls1 += a1; lq1 += a1 * a1;
      ls2 += a2; lq2 += a2 * a2; ls3 += a3; lq3 += a3 * a3;
    }
  }
  if (lane < 16) {
    atomicAdd(&ssum[4 * ll + 0], ls0); atomicAdd(&ssq[4 * ll + 0], lq0);
    atomicAdd(&ssum[4 * ll + 1], ls1); atomicAdd(&ssq[4 * ll + 1], lq1);
    atomicAdd(&ssum[4 * ll + 2], ls2); atomicAdd(&ssq[4 * ll + 2], lq2);
    atomicAdd(&ssum[4 * ll + 3], ls3); atomicAdd(&ssq[4 * ll + 3], lq3);
  }
  __syncthreads();
  if (tid < 64) {
    int col = chunk * 64 + tid;
    int sp = g & 7;
    atomicAdd(&stat[col * 8 + sp], ssum[tid]);
    atomicAdd(&stat[(DFEAT + col) * 8 + sp], ssq[tid]);
  }
}

// ---------------- gather 2 masked nodes/sample + inline BN6 -> flat f32 -----
__global__ void gather_kernel(const int* __restrict__ mask, const ushort16* __restrict__ R5,
                              const float* __restrict__ stat, const float* __restrict__ g,
                              const float* __restrict__ bb, float invN,
                              float* __restrict__ flat) {
  __shared__ int smin, smax;
  int b = blockIdx.x, t = threadIdx.x;  // 384
  if (t == 0) { smin = 1 << 30; smax = -1; }
  __syncthreads();
  for (int p = t; p < 512; p += 384)
    if (mask[b * 512 + p]) { atomicMin(&smin, p); atomicMax(&smax, p); }
  __syncthreads();
  float s = 0.f, q = 0.f;
  for (int i = 0; i < 8; ++i) { s += stat[t * 8 + i]; q += stat[(DFEAT + t) * 8 + i]; }
  float mean = s * invN, var = q * invN - mean * mean;
  float a = g[t] * rsqrtf(var + 1e-5f), sh = bb[t] - a * mean;
  int sel[2] = {smin, smax};
  for (int j = 0; j < 2; ++j) {
    float v = bf2f(R5[(size_t)(b * 512 + sel[j]) * DFEAT + t]);
    flat[(size_t)b * 768 + j * DFEAT + t] = a * v + sh;
  }
}

// ---------------- tail ------------------------------------------------------
__global__ void cat_gemm_kernel(const float* __restrict__ flat, const float* __restrict__ Wc,
                                const float* __restrict__ bc, float* __restrict__ out) {
  int t = threadIdx.x;
  int j = blockIdx.x * 64 + (t & 63);
  int b = blockIdx.y * 16 + (t >> 6);
  const float* fr = flat + (size_t)b * 768;
  float acc = bc[j];
#pragma unroll 4
  for (int k = 0; k < 768; ++k) acc += fr[k] * Wc[(size_t)k * 768 + j];
  out[(size_t)b * 768 + j] = fmaxf(acc, 0.f);
}
__global__ void bnstats_kernel(const float* __restrict__ catrelu, const float* __restrict__ Hsent,
                               const float* __restrict__ g, const float* __restrict__ bb,
                               float* __restrict__ aff) {
  int c = blockIdx.x * 64 + threadIdx.x;
  float s1 = 0, q1 = 0, s2 = 0, q2 = 0;
  for (int b = 0; b < 64; ++b) {
    float v = catrelu[b * 768 + c]; s1 += v; q1 += v * v;
    float h = Hsent[b * 768 + c];   s2 += h; q2 += h * h;
  }
  const float inv = 1.0f / 64.0f;
  float m1 = s1 * inv, var1 = q1 * inv - m1 * m1;
  float a1 = g[c] * rsqrtf(var1 + 1e-5f);
  aff[c] = a1; aff[768 + c] = bb[c] - a1 * m1;
  float m2 = s2 * inv, var2 = q2 * inv - m2 * m2;
  float a2 = g[768 + c] * rsqrtf(var2 + 1e-5f);
  aff[1536 + c] = a2; aff[2304 + c] = bb[768 + c] - a2 * m2;
}
__global__ void final_kernel(const float* __restrict__ Hs, const float* __restrict__ catrelu,
                             const float* __restrict__ aff, const float* __restrict__ w_out,
                             const float* __restrict__ b_out, float* __restrict__ out) {
  __shared__ float red[12];
  int b = blockIdx.x, t = threadIdx.x;  // 256
  float p0 = 0, p1 = 0, p2 = 0;
  for (int k = t; k < 768; k += 256) {
    float att = (aff[1536 + k] * Hs[b * 768 + k] + aff[2304 + k]) +
                (aff[k] * catrelu[b * 768 + k] + aff[768 + k]);
    p0 += att * w_out[k * 3 + 0];
    p1 += att * w_out[k * 3 + 1];
    p2 += att * w_out[k * 3 + 2];
  }
  for (int off = 32; off > 0; off >>= 1) {
    p0 += __shfl_down(p0, off, 64);
    p1 += __shfl_down(p1, off, 64);
    p2 += __shfl_down(p2, off, 64);
  }
  int wv = t >> 6;
  if ((t & 63) == 0) { red[wv * 3 + 0] = p0; red[wv * 3 + 1] = p1; red[wv * 3 + 2] = p2; }
  __syncthreads();
  if (t == 0) {
    out[b * 3 + 0] = b_out[0] + red[0] + red[3] + red[6] + red[9];
    out[b * 3 + 1] = b_out[1] + red[1] + red[4] + red[7] + red[10];
    out[b * 3 + 2] = b_out[2] + red[2] + red[5] + red[8] + red[11];
  }
}

// ============================================================================
extern "C" void kernel_launch(void* const* d_in, const int* in_sizes, int n_in,
                              void* d_out, int out_size, void* d_ws, size_t ws_size,
                              hipStream_t stream) {
  const float* last_h  = (const float*)d_in[0];
  const float* first_h = (const float*)d_in[1];
  const float* x_nodes = (const float*)d_in[2];
  const int*   edges   = (const int*)d_in[3];
  const int*   mask    = (const int*)d_in[4];
  const float* w_pre1  = (const float*)d_in[5];
  const float* b_pre1  = (const float*)d_in[6];
  const float* w_pre2  = (const float*)d_in[7];
  const float* b_pre2  = (const float*)d_in[8];
  const float* w_conv  = (const float*)d_in[9];
  const float* b_conv  = (const float*)d_in[10];
  const float* bng_g   = (const float*)d_in[11];
  const float* bng_b   = (const float*)d_in[12];
  const float* w_post1 = (const float*)d_in[13];
  const float* b_post1 = (const float*)d_in[14];
  const float* w_post2 = (const float*)d_in[15];
  const float* b_post2 = (const float*)d_in[16];
  const float* w_cat   = (const float*)d_in[17];
  const float* b_cat   = (const float*)d_in[18];
  const float* bn_g    = (const float*)d_in[19];
  const float* bn_b    = (const float*)d_in[20];
  const float* w_out   = (const float*)d_in[21];
  const float* b_out   = (const float*)d_in[22];
  float* out = (float*)d_out;

  const int E = in_sizes[3] / 2;  // 1048576
  const int* e_src = edges;
  const int* e_dst = edges + E;
  const int degB = (E + 255) / 256;

  char* w = (char*)d_ws;
  size_t off = 0;
  auto alloc = [&](size_t bytes) { size_t p = off; off = (off + bytes + 255) & ~(size_t)255; return p; };
  ushort16* buf0   = (ushort16*)(w + alloc((size_t)NNODES * DFEAT * 2));  // A0, R2, RC, R5
  ushort16* buf1   = (ushort16*)(w + alloc((size_t)NNODES * DFEAT * 2));  // R1, XW', R4
  int*    csr      = (int*)(w + alloc((size_t)E * 4));
  int*    rowstart = (int*)(w + alloc((size_t)(NNODES + 1) * 4));
  int*    cursor   = (int*)(w + alloc((size_t)NNODES * 4));
  float*  disq     = (float*)(w + alloc((size_t)NNODES * 4));
  ushort16* BT     = (ushort16*)(w + alloc((size_t)DFEAT * DFEAT * 2));
  float*  biasx    = (float*)(w + alloc(DFEAT * 4));
  float*  flat     = (float*)(w + alloc(64 * 768 * 4));
  float*  catrelu  = (float*)(w + alloc(64 * 768 * 4));
  float*  aff64    = (float*)(w + alloc(4 * 768 * 4));
  float*  Hpart    = (float*)(w + alloc((size_t)16 * 64 * 768 * 4));
  float*  Hsent    = (float*)(w + alloc(64 * 768 * 4));
  size_t zoff = off;
  int*   degcnt = (int*)(w + alloc((size_t)NNODES * 4));
  float* stats  = (float*)(w + alloc((size_t)5 * 768 * 8 * 4));
  size_t zbytes = off - zoff;

  hipMemsetAsync(w + zoff, 0, zbytes, stream);

  const float invN = 1.0f / (float)NNODES;
  float* st0 = stats + 0 * 768 * 8;
  float* st1 = stats + 1 * 768 * 8;
  float* st2 = stats + 2 * 768 * 8;
  float* st3 = stats + 3 * 768 * 8;
  float* st4 = stats + 4 * 768 * 8;

  // ---- phase A: fused independent prep ----
  prep_kernel<<<8192 + degB + 3072, 256, 0, stream>>>(x_nodes, buf0, e_dst, degcnt, E, degB,
                                                      last_h, first_h, Hpart);
  xform_w_kernel<<<DFEAT, 128, 0, stream>>>(w_pre1, b_pre1, nullptr, nullptr, nullptr, invN, BT, biasx, 300, KPAD1, DFEAT);
  scan_kernel<<<1, 1024, 0, stream>>>(degcnt, rowstart, cursor, disq);
  scatter_kernel<<<degB + 192, 256, 0, stream>>>(e_src, e_dst, cursor, csr, E, degB, Hpart, Hsent);

  dim3 ggrid(NNODES / BM, DFEAT / BN);

  // ---- GEMM1: R1 = relu(x @ W1 + b1), stats->BN0 ----
  gemm_bf16<true, true, false><<<ggrid, 256, 0, stream>>>(buf0, KPAD1, BT, KPAD1, biasx, nullptr, buf1, DFEAT, KPAD1, st0);
  xform_w_kernel<<<DFEAT, 128, 0, stream>>>(w_pre2, b_pre2, st0, bng_g + 0 * DFEAT, bng_b + 0 * DFEAT, invN, BT, biasx, DFEAT, DFEAT, DFEAT);

  // ---- GEMM2: R2 = relu(BN0(R1) @ W2 + b2), stats->BN1 ----
  gemm_bf16<true, true, false><<<ggrid, 256, 0, stream>>>(buf1, DFEAT, BT, DFEAT, biasx, nullptr, buf0, DFEAT, DFEAT, st1);
  xform_w_kernel<<<DFEAT, 128, 0, stream>>>(w_conv + 2 * DFEAT * DFEAT, nullptr, st1, bng_g + 1 * DFEAT, bng_b + 1 * DFEAT, invN, BT, biasx, DFEAT, DFEAT, DFEAT);

  // ---- GEMM3: XW' = disq[row] * (BN1(R2) @ Wc)  (conv i=2 only survives) ----
  gemm_bf16<false, false, true><<<ggrid, 256, 0, stream>>>(buf0, DFEAT, BT, DFEAT, biasx, disq, buf1, DFEAT, DFEAT, nullptr);

  // ---- aggregation (chunked, XCD-affine, dual-edge uint2), stats->BN4 ----
  aggregate_kernel<<<8192, 256, 0, stream>>>((const uint32*)buf1, csr, rowstart, disq, b_conv + 2 * DFEAT, (uint32*)buf0, st2);
  xform_w_kernel<<<DFEAT, 128, 0, stream>>>(w_post1, b_post1, st2, bng_g + 4 * DFEAT, bng_b + 4 * DFEAT, invN, BT, biasx, DFEAT, DFEAT, DFEAT);

  // ---- GEMM4: R4 = relu(BN4(RC) @ Wp1 + bp1), stats->BN5 ----
  gemm_bf16<true, true, false><<<ggrid, 256, 0, stream>>>(buf0, DFEAT, BT, DFEAT, biasx, nullptr, buf1, DFEAT, DFEAT, st3);
  xform_w_kernel<<<DFEAT, 128, 0, stream>>>(w_post2, b_post2, st3, bng_g + 5 * DFEAT, bng_b + 5 * DFEAT, invN, BT, biasx, DFEAT, DFEAT, DFEAT);

  // ---- GEMM5: R5 = relu(BN5(R4) @ Wp2 + bp2), stats->BN6 ----
  gemm_bf16<true, true, false><<<ggrid, 256, 0, stream>>>(buf1, DFEAT, BT, DFEAT, biasx, nullptr, buf0, DFEAT, DFEAT, st4);

  // ---- gather (BN6 inline) + tail ----
  gather_kernel<<<64, DFEAT, 0, stream>>>(mask, buf0, st4, bng_g + 6 * DFEAT, bng_b + 6 * DFEAT, invN, flat);
  cat_gemm_kernel<<<dim3(12, 4), 1024, 0, stream>>>(flat, w_cat, b_cat, catrelu);
  bnstats_kernel<<<12, 64, 0, stream>>>(catrelu, Hsent, bn_g, bn_b, aff64);
  final_kernel<<<64, 256, 0, stream>>>(Hsent, catrelu, aff64, w_out, b_out, out);
}

// Round 3
// 853.245 us; speedup vs baseline: 1.1096x; 1.1096x over previous
//
#include <hip/hip_runtime.h>

typedef unsigned int uint32;
typedef unsigned short ushort16;

typedef __attribute__((ext_vector_type(8))) short bf16x8;
typedef __attribute__((ext_vector_type(4))) float f32x4;

#define NNODES 32768
#define DFEAT 384
#define KPAD1 320

__device__ __forceinline__ float bf2f(ushort16 u) {
  union { uint32 i; float f; } x; x.i = ((uint32)u) << 16; return x.f;
}
__device__ __forceinline__ float bflo(uint32 v) {
  union { uint32 i; float f; } x; x.i = v << 16; return x.f;
}
__device__ __forceinline__ float bfhi(uint32 v) {
  union { uint32 i; float f; } x; x.i = v & 0xffff0000u; return x.f;
}
__device__ __forceinline__ ushort16 f2bf(float f) {
  union { float f; uint32 i; } x; x.f = f;
  uint32 r = (x.i + 0x7fffu + ((x.i >> 16) & 1u)) >> 16;
  return (ushort16)r;
}

// ---------------- fused prep: convert_x + deg_count + sent_mean ------------
__global__ __launch_bounds__(256) void prep_kernel(
    const float* __restrict__ X, ushort16* __restrict__ A0,
    const int* __restrict__ dst, int* __restrict__ cnt, int E, int degB,
    const float* __restrict__ last, const float* __restrict__ first,
    float* __restrict__ Hpart) {
  int bx = blockIdx.x;
  int tid = threadIdx.x;
  if (bx < 8192) {
    int row = bx * 4 + (tid >> 6);
    int lane = tid & 63;
    const float* xr = X + (size_t)row * 300;
    ushort16* ar = A0 + (size_t)row * KPAD1;
#pragma unroll
    for (int i = 0; i < 5; ++i) {
      int col = lane + i * 64;
      float v = (col < 300) ? xr[col] : 0.f;
      ar[col] = f2bf(v);
    }
  } else if (bx < 8192 + degB) {
    int e = (bx - 8192) * 256 + tid;
    if (e < E) atomicAdd(&cnt[dst[e]], 1);
  } else {
    int idx = bx - 8192 - degB;        // [0, 3072): es*1024 + sc*64 + b
    int b = idx & 63, sc = (idx >> 6) & 15, es = idx >> 10;
    int e = es * 256 + tid;
    int s0 = sc * 32;
    const float* pl = last + ((size_t)b * 512 + s0) * 768 + e;
    const float* pf = first + ((size_t)b * 512 + s0) * 768 + e;
    float a0 = 0.f, a1 = 0.f, a2 = 0.f, a3 = 0.f;
    for (int i = 0; i < 32; i += 4) {
      a0 += pl[(i + 0) * 768] + pf[(i + 0) * 768];
      a1 += pl[(i + 1) * 768] + pf[(i + 1) * 768];
      a2 += pl[(i + 2) * 768] + pf[(i + 2) * 768];
      a3 += pl[(i + 3) * 768] + pf[(i + 3) * 768];
    }
    Hpart[((size_t)sc * 64 + b) * 768 + e] = a0 + a1 + a2 + a3;
  }
}

// ---------------- scan (+ disq folded) --------------------------------------
__global__ void scan_kernel(const int* __restrict__ cnt, int* __restrict__ row_start,
                            int* __restrict__ cursor, float* __restrict__ disq) {
  __shared__ int buf[1024];
  int t = threadIdx.x;
  int base = t * 32;
  int s = 0;
  for (int i = 0; i < 32; ++i) {
    int c = cnt[base + i];
    s += c;
    disq[base + i] = rsqrtf((float)c + 1.0f);  // +1 self loop
  }
  buf[t] = s; __syncthreads();
  int x = s;
  for (int off = 1; off < 1024; off <<= 1) {
    int v = (t >= off) ? buf[t - off] : 0;
    __syncthreads();
    x += v; buf[t] = x;
    __syncthreads();
  }
  int run = x - s;
  for (int i = 0; i < 32; ++i) {
    row_start[base + i] = run; cursor[base + i] = run;
    run += cnt[base + i];
  }
  if (t == 1023) row_start[NNODES] = run;
}

// ---------------- scatter (+ hsent folded) ----------------------------------
__global__ __launch_bounds__(256) void scatter_kernel(
    const int* __restrict__ src, const int* __restrict__ dst,
    int* __restrict__ cursor, int* __restrict__ csr, int E, int degB,
    const float* __restrict__ Hpart, float* __restrict__ Hsent) {
  int bx = blockIdx.x, t = threadIdx.x;
  if (bx < degB) {
    int e = bx * 256 + t;
    if (e < E) {
      int d = dst[e];
      int pos = atomicAdd(&cursor[d], 1);
      csr[pos] = src[e];
    }
  } else {
    int idx = bx - degB;               // [0, 192): es*64 + b
    int b = idx & 63, es = idx >> 6;
    int e = es * 256 + t;
    float h = 0.f;
#pragma unroll
    for (int sc = 0; sc < 16; ++sc) h += Hpart[((size_t)sc * 64 + b) * 768 + e];
    Hsent[(size_t)b * 768 + e] = h * (0.5f / 512.f);
  }
}

// ---------------- weight transform with inline BN-affine from spread stats --
__global__ void xform_w_kernel(const float* __restrict__ W, const float* __restrict__ bias,
                               const float* __restrict__ stat, const float* __restrict__ g,
                               const float* __restrict__ bb, float invN,
                               ushort16* __restrict__ BT, float* __restrict__ bias_out,
                               int K, int Kpad, int Nw) {
  __shared__ float red[128];
  int n = blockIdx.x, t = threadIdx.x;
  float part = 0.f;
  for (int k = t; k < Kpad; k += 128) {
    ushort16 o = 0; float contrib = 0.f;
    if (k < K) {
      float ak = 1.f, shk = 0.f;
      if (stat) {
        float s = 0.f, q = 0.f;
        for (int i = 0; i < 8; ++i) { s += stat[k * 8 + i]; q += stat[(DFEAT + k) * 8 + i]; }
        float mean = s * invN, var = q * invN - mean * mean;
        ak = g[k] * rsqrtf(var + 1e-5f);
        shk = bb[k] - ak * mean;
      }
      float w = W[(size_t)k * Nw + n];
      o = f2bf(ak * w);
      contrib = shk * w;
    }
    BT[(size_t)n * Kpad + k] = o;
    part += contrib;
  }
  red[t] = part; __syncthreads();
  for (int off = 64; off > 0; off >>= 1) {
    if (t < off) red[t] += red[t + off];
    __syncthreads();
  }
  if (t == 0) bias_out[n] = (bias ? bias[n] : 0.f) + red[0];
}

// ---------------- MFMA bf16 GEMM with fused stats / row-scale ---------------
#define BM 128
#define BN 128
#define BKT 32
#define LDT 40  // BKT + 8 pad shorts

template <bool RELU, bool STATS, bool RSCALE>
__global__ __launch_bounds__(256) void gemm_bf16(
    const ushort16* __restrict__ A, int lda, const ushort16* __restrict__ BT, int ldb,
    const float* __restrict__ bias, const float* __restrict__ rowscale,
    ushort16* __restrict__ C, int Ntot, int K, float* __restrict__ stat) {
  __shared__ __attribute__((aligned(16))) ushort16 As[BM * LDT];
  __shared__ __attribute__((aligned(16))) ushort16 Bs[BN * LDT];
  __shared__ float ssum[BN], ssq[BN];
  int bm0 = blockIdx.x * BM, bn0 = blockIdx.y * BN;
  int tid = threadIdx.x;
  if (STATS) {
    if (tid < BN) { ssum[tid] = 0.f; ssq[tid] = 0.f; }
  }
  int lane = tid & 63, wave = tid >> 6;
  int wm = (wave & 1) * 64, wn = (wave >> 1) * 64;
  int l15 = lane & 15, quad = lane >> 4;

  f32x4 acc[4][4];
  for (int i = 0; i < 4; ++i)
    for (int j = 0; j < 4; ++j) acc[i][j] = (f32x4)0.f;

  for (int kk = 0; kk < K; kk += BKT) {
    __syncthreads();
    for (int i = 0; i < 2; ++i) {
      int chunk = tid + i * 256;
      int row = chunk >> 2, cc = chunk & 3;
      uint4 va = *(const uint4*)(A + (size_t)(bm0 + row) * lda + kk + cc * 8);
      *(uint4*)(&As[row * LDT + cc * 8]) = va;
      uint4 vb = *(const uint4*)(BT + (size_t)(bn0 + row) * ldb + kk + cc * 8);
      *(uint4*)(&Bs[row * LDT + cc * 8]) = vb;
    }
    __syncthreads();
    bf16x8 af[4], bfr[4];
    for (int mi = 0; mi < 4; ++mi)
      af[mi] = *(const bf16x8*)(&As[(wm + mi * 16 + l15) * LDT + quad * 8]);
    for (int ni = 0; ni < 4; ++ni)
      bfr[ni] = *(const bf16x8*)(&Bs[(wn + ni * 16 + l15) * LDT + quad * 8]);
    for (int mi = 0; mi < 4; ++mi)
      for (int ni = 0; ni < 4; ++ni)
        acc[mi][ni] = __builtin_amdgcn_mfma_f32_16x16x32_bf16(af[mi], bfr[ni], acc[mi][ni], 0, 0, 0);
  }
  for (int ni = 0; ni < 4; ++ni) {
    int coll = wn + ni * 16 + l15;
    int col = bn0 + coll;
    float bv = bias[col];
    float s = 0.f, q = 0.f;
    for (int mi = 0; mi < 4; ++mi) {
      for (int r = 0; r < 4; ++r) {
        int row = bm0 + wm + mi * 16 + quad * 4 + r;
        float v = acc[mi][ni][r] + bv;
        if (RELU) v = fmaxf(v, 0.f);
        if (RSCALE) v *= rowscale[row];
        C[(size_t)row * Ntot + col] = f2bf(v);
        if (STATS) { s += v; q += v * v; }
      }
    }
    if (STATS) { atomicAdd(&ssum[coll], s); atomicAdd(&ssq[coll], q); }
  }
  if (STATS) {
    __syncthreads();
    int sp = blockIdx.x & 7;
    if (tid < BN) {
      atomicAdd(&stat[(bn0 + tid) * 8 + sp], ssum[tid]);
      atomicAdd(&stat[(DFEAT + bn0 + tid) * 8 + sp], ssq[tid]);
    }
  }
}

// ---------------- balanced XCD-affine GCN aggregation -----------------------
// Proven r1 inner loop (32-lane uint32 gather). NEW: balanced unit mapping.
// 6 chunks x 1024 groups = 6144 units; XCD k (bx&7) owns units [768k,768k+768)
// -> every XCD does exactly 768 units (was 512/1024 split = 2x imbalance).
// Each XCD touches <=2 chunk slices (<=8MB), sequential in launch order.
__global__ void __launch_bounds__(256) aggregate_kernel(
    const uint32* __restrict__ XWs, const int* __restrict__ csr,
    const int* __restrict__ row_start, const float* __restrict__ disq,
    const float* __restrict__ bconv, uint32* __restrict__ RC2,
    float* __restrict__ stat) {
  int bx = blockIdx.x;                 // grid 6144
  int unit = (bx & 7) * 768 + (bx >> 3);
  int chunk = unit >> 10;              // [0,6)
  int g = unit & 1023;                 // [0,1024)
  __shared__ float ssum[64], ssq[64];
  int tid = threadIdx.x;
  if (tid < 64) { ssum[tid] = 0.f; ssq[tid] = 0.f; }
  __syncthreads();
  int lane = tid & 63, wave = tid >> 6;
  int half = lane >> 5, cl = lane & 31;
  int hb = half << 5;
  int cbase = chunk * 32;
  float b0 = bconv[chunk * 64 + 2 * cl], b1 = bconv[chunk * 64 + 2 * cl + 1];
  float ls0 = 0.f, ls1 = 0.f, lq0 = 0.f, lq1 = 0.f;
  int nodebase = (g * 4 + wave) * 8;
  for (int ni = 0; ni < 8; ++ni) {
    int n = nodebase + ni;
    int beg = row_start[n], end = row_start[n + 1];
    int deg = end - beg;
    int len0 = (deg + 1) >> 1;  // half 0 gets the longer part
    int myBeg = beg + (half ? len0 : 0);
    int myLen = half ? (deg - len0) : len0;
    float a0, a1;
    if (half == 0) {
      uint32 v = XWs[(size_t)n * 192 + cbase + cl];
      a0 = bflo(v); a1 = bfhi(v);
    } else { a0 = 0.f; a1 = 0.f; }
    for (int bb0 = 0; bb0 < len0; bb0 += 32) {
      int rem = myLen - bb0;
      int idx = (cl < rem) ? csr[myBeg + bb0 + cl] : -1;
      int jmax = min(32, len0 - bb0);  // uniform over wave
      int j = 0;
      for (; j + 8 <= jmax; j += 8) {
        uint32 v[8];
#pragma unroll
        for (int jj = 0; jj < 8; ++jj) {
          int s = __shfl(idx, hb + j + jj, 64);
          int sa = (s < 0) ? 0 : s;                 // safe address
          uint32 m = (s < 0) ? 0u : 0xffffffffu;    // zero-mask invalid
          v[jj] = XWs[(size_t)sa * 192 + cbase + cl] & m;
        }
#pragma unroll
        for (int jj = 0; jj < 8; ++jj) { a0 += bflo(v[jj]); a1 += bfhi(v[jj]); }
      }
      for (; j < jmax; ++j) {
        int s = __shfl(idx, hb + j, 64);
        int sa = (s < 0) ? 0 : s;
        uint32 m = (s < 0) ? 0u : 0xffffffffu;
        uint32 v = XWs[(size_t)sa * 192 + cbase + cl] & m;
        a0 += bflo(v); a1 += bfhi(v);
      }
    }
    a0 += __shfl_xor(a0, 32, 64);
    a1 += __shfl_xor(a1, 32, 64);
    if (half == 0) {
      float din = disq[n];
      a0 = fmaxf(din * a0 + b0, 0.f);
      a1 = fmaxf(din * a1 + b1, 0.f);
      RC2[(size_t)n * 192 + cbase + cl] = (uint32)f2bf(a0) | ((uint32)f2bf(a1) << 16);
      ls0 += a0; lq0 += a0 * a0; ls1 += a1; lq1 += a1 * a1;
    }
  }
  if (half == 0) {
    atomicAdd(&ssum[2 * cl], ls0); atomicAdd(&ssum[2 * cl + 1], ls1);
    atomicAdd(&ssq[2 * cl], lq0);  atomicAdd(&ssq[2 * cl + 1], lq1);
  }
  __syncthreads();
  if (tid < 64) {
    int col = chunk * 64 + tid;
    int sp = g & 7;
    atomicAdd(&stat[col * 8 + sp], ssum[tid]);
    atomicAdd(&stat[(DFEAT + col) * 8 + sp], ssq[tid]);
  }
}

// ---------------- gather 2 masked nodes/sample + inline BN6 -> flat f32 -----
__global__ void gather_kernel(const int* __restrict__ mask, const ushort16* __restrict__ R5,
                              const float* __restrict__ stat, const float* __restrict__ g,
                              const float* __restrict__ bb, float invN,
                              float* __restrict__ flat) {
  __shared__ int smin, smax;
  int b = blockIdx.x, t = threadIdx.x;  // 384
  if (t == 0) { smin = 1 << 30; smax = -1; }
  __syncthreads();
  for (int p = t; p < 512; p += 384)
    if (mask[b * 512 + p]) { atomicMin(&smin, p); atomicMax(&smax, p); }
  __syncthreads();
  float s = 0.f, q = 0.f;
  for (int i = 0; i < 8; ++i) { s += stat[t * 8 + i]; q += stat[(DFEAT + t) * 8 + i]; }
  float mean = s * invN, var = q * invN - mean * mean;
  float a = g[t] * rsqrtf(var + 1e-5f), sh = bb[t] - a * mean;
  int sel[2] = {smin, smax};
  for (int j = 0; j < 2; ++j) {
    float v = bf2f(R5[(size_t)(b * 512 + sel[j]) * DFEAT + t]);
    flat[(size_t)b * 768 + j * DFEAT + t] = a * v + sh;
  }
}

// ---------------- tail ------------------------------------------------------
__global__ void cat_gemm_kernel(const float* __restrict__ flat, const float* __restrict__ Wc,
                                const float* __restrict__ bc, float* __restrict__ out) {
  int t = threadIdx.x;
  int j = blockIdx.x * 64 + (t & 63);
  int b = blockIdx.y * 16 + (t >> 6);
  const float* fr = flat + (size_t)b * 768;
  float acc = bc[j];
#pragma unroll 4
  for (int k = 0; k < 768; ++k) acc += fr[k] * Wc[(size_t)k * 768 + j];
  out[(size_t)b * 768 + j] = fmaxf(acc, 0.f);
}
__global__ void bnstats_kernel(const float* __restrict__ catrelu, const float* __restrict__ Hsent,
                               const float* __restrict__ g, const float* __restrict__ bb,
                               float* __restrict__ aff) {
  int c = blockIdx.x * 64 + threadIdx.x;
  float s1 = 0, q1 = 0, s2 = 0, q2 = 0;
  for (int b = 0; b < 64; ++b) {
    float v = catrelu[b * 768 + c]; s1 += v; q1 += v * v;
    float h = Hsent[b * 768 + c];   s2 += h; q2 += h * h;
  }
  const float inv = 1.0f / 64.0f;
  float m1 = s1 * inv, var1 = q1 * inv - m1 * m1;
  float a1 = g[c] * rsqrtf(var1 + 1e-5f);
  aff[c] = a1; aff[768 + c] = bb[c] - a1 * m1;
  float m2 = s2 * inv, var2 = q2 * inv - m2 * m2;
  float a2 = g[768 + c] * rsqrtf(var2 + 1e-5f);
  aff[1536 + c] = a2; aff[2304 + c] = bb[768 + c] - a2 * m2;
}
__global__ void final_kernel(const float* __restrict__ Hs, const float* __restrict__ catrelu,
                             const float* __restrict__ aff, const float* __restrict__ w_out,
                             const float* __restrict__ b_out, float* __restrict__ out) {
  __shared__ float red[12];
  int b = blockIdx.x, t = threadIdx.x;  // 256
  float p0 = 0, p1 = 0, p2 = 0;
  for (int k = t; k < 768; k += 256) {
    float att = (aff[1536 + k] * Hs[b * 768 + k] + aff[2304 + k]) +
                (aff[k] * catrelu[b * 768 + k] + aff[768 + k]);
    p0 += att * w_out[k * 3 + 0];
    p1 += att * w_out[k * 3 + 1];
    p2 += att * w_out[k * 3 + 2];
  }
  for (int off = 32; off > 0; off >>= 1) {
    p0 += __shfl_down(p0, off, 64);
    p1 += __shfl_down(p1, off, 64);
    p2 += __shfl_down(p2, off, 64);
  }
  int wv = t >> 6;
  if ((t & 63) == 0) { red[wv * 3 + 0] = p0; red[wv * 3 + 1] = p1; red[wv * 3 + 2] = p2; }
  __syncthreads();
  if (t == 0) {
    out[b * 3 + 0] = b_out[0] + red[0] + red[3] + red[6] + red[9];
    out[b * 3 + 1] = b_out[1] + red[1] + red[4] + red[7] + red[10];
    out[b * 3 + 2] = b_out[2] + red[2] + red[5] + red[8] + red[11];
  }
}

// ============================================================================
extern "C" void kernel_launch(void* const* d_in, const int* in_sizes, int n_in,
                              void* d_out, int out_size, void* d_ws, size_t ws_size,
                              hipStream_t stream) {
  const float* last_h  = (const float*)d_in[0];
  const float* first_h = (const float*)d_in[1];
  const float* x_nodes = (const float*)d_in[2];
  const int*   edges   = (const int*)d_in[3];
  const int*   mask    = (const int*)d_in[4];
  const float* w_pre1  = (const float*)d_in[5];
  const float* b_pre1  = (const float*)d_in[6];
  const float* w_pre2  = (const float*)d_in[7];
  const float* b_pre2  = (const float*)d_in[8];
  const float* w_conv  = (const float*)d_in[9];
  const float* b_conv  = (const float*)d_in[10];
  const float* bng_g   = (const float*)d_in[11];
  const float* bng_b   = (const float*)d_in[12];
  const float* w_post1 = (const float*)d_in[13];
  const float* b_post1 = (const float*)d_in[14];
  const float* w_post2 = (const float*)d_in[15];
  const float* b_post2 = (const float*)d_in[16];
  const float* w_cat   = (const float*)d_in[17];
  const float* b_cat   = (const float*)d_in[18];
  const float* bn_g    = (const float*)d_in[19];
  const float* bn_b    = (const float*)d_in[20];
  const float* w_out   = (const float*)d_in[21];
  const float* b_out   = (const float*)d_in[22];
  float* out = (float*)d_out;

  const int E = in_sizes[3] / 2;  // 1048576
  const int* e_src = edges;
  const int* e_dst = edges + E;
  const int degB = (E + 255) / 256;

  char* w = (char*)d_ws;
  size_t off = 0;
  auto alloc = [&](size_t bytes) { size_t p = off; off = (off + bytes + 255) & ~(size_t)255; return p; };
  ushort16* buf0   = (ushort16*)(w + alloc((size_t)NNODES * DFEAT * 2));  // A0, R2, RC, R5
  ushort16* buf1   = (ushort16*)(w + alloc((size_t)NNODES * DFEAT * 2));  // R1, XW', R4
  int*    csr      = (int*)(w + alloc((size_t)E * 4));
  int*    rowstart = (int*)(w + alloc((size_t)(NNODES + 1) * 4));
  int*    cursor   = (int*)(w + alloc((size_t)NNODES * 4));
  float*  disq     = (float*)(w + alloc((size_t)NNODES * 4));
  ushort16* BT     = (ushort16*)(w + alloc((size_t)DFEAT * DFEAT * 2));
  float*  biasx    = (float*)(w + alloc(DFEAT * 4));
  float*  flat     = (float*)(w + alloc(64 * 768 * 4));
  float*  catrelu  = (float*)(w + alloc(64 * 768 * 4));
  float*  aff64    = (float*)(w + alloc(4 * 768 * 4));
  float*  Hpart    = (float*)(w + alloc((size_t)16 * 64 * 768 * 4));
  float*  Hsent    = (float*)(w + alloc(64 * 768 * 4));
  size_t zoff = off;
  int*   degcnt = (int*)(w + alloc((size_t)NNODES * 4));
  float* stats  = (float*)(w + alloc((size_t)5 * 768 * 8 * 4));
  size_t zbytes = off - zoff;

  hipMemsetAsync(w + zoff, 0, zbytes, stream);

  const float invN = 1.0f / (float)NNODES;
  float* st0 = stats + 0 * 768 * 8;
  float* st1 = stats + 1 * 768 * 8;
  float* st2 = stats + 2 * 768 * 8;
  float* st3 = stats + 3 * 768 * 8;
  float* st4 = stats + 4 * 768 * 8;

  // ---- phase A: fused independent prep ----
  prep_kernel<<<8192 + degB + 3072, 256, 0, stream>>>(x_nodes, buf0, e_dst, degcnt, E, degB,
                                                      last_h, first_h, Hpart);
  xform_w_kernel<<<DFEAT, 128, 0, stream>>>(w_pre1, b_pre1, nullptr, nullptr, nullptr, invN, BT, biasx, 300, KPAD1, DFEAT);
  scan_kernel<<<1, 1024, 0, stream>>>(degcnt, rowstart, cursor, disq);
  scatter_kernel<<<degB + 192, 256, 0, stream>>>(e_src, e_dst, cursor, csr, E, degB, Hpart, Hsent);

  dim3 ggrid(NNODES / BM, DFEAT / BN);

  // ---- GEMM1: R1 = relu(x @ W1 + b1), stats->BN0 ----
  gemm_bf16<true, true, false><<<ggrid, 256, 0, stream>>>(buf0, KPAD1, BT, KPAD1, biasx, nullptr, buf1, DFEAT, KPAD1, st0);
  xform_w_kernel<<<DFEAT, 128, 0, stream>>>(w_pre2, b_pre2, st0, bng_g + 0 * DFEAT, bng_b + 0 * DFEAT, invN, BT, biasx, DFEAT, DFEAT, DFEAT);

  // ---- GEMM2: R2 = relu(BN0(R1) @ W2 + b2), stats->BN1 ----
  gemm_bf16<true, true, false><<<ggrid, 256, 0, stream>>>(buf1, DFEAT, BT, DFEAT, biasx, nullptr, buf0, DFEAT, DFEAT, st1);
  xform_w_kernel<<<DFEAT, 128, 0, stream>>>(w_conv + 2 * DFEAT * DFEAT, nullptr, st1, bng_g + 1 * DFEAT, bng_b + 1 * DFEAT, invN, BT, biasx, DFEAT, DFEAT, DFEAT);

  // ---- GEMM3: XW' = disq[row] * (BN1(R2) @ Wc)  (conv i=2 only survives) ----
  gemm_bf16<false, false, true><<<ggrid, 256, 0, stream>>>(buf0, DFEAT, BT, DFEAT, biasx, disq, buf1, DFEAT, DFEAT, nullptr);

  // ---- aggregation (balanced XCD-affine), stats->BN4 ----
  aggregate_kernel<<<6144, 256, 0, stream>>>((const uint32*)buf1, csr, rowstart, disq, b_conv + 2 * DFEAT, (uint32*)buf0, st2);
  xform_w_kernel<<<DFEAT, 128, 0, stream>>>(w_post1, b_post1, st2, bng_g + 4 * DFEAT, bng_b + 4 * DFEAT, invN, BT, biasx, DFEAT, DFEAT, DFEAT);

  // ---- GEMM4: R4 = relu(BN4(RC) @ Wp1 + bp1), stats->BN5 ----
  gemm_bf16<true, true, false><<<ggrid, 256, 0, stream>>>(buf0, DFEAT, BT, DFEAT, biasx, nullptr, buf1, DFEAT, DFEAT, st3);
  xform_w_kernel<<<DFEAT, 128, 0, stream>>>(w_post2, b_post2, st3, bng_g + 5 * DFEAT, bng_b + 5 * DFEAT, invN, BT, biasx, DFEAT, DFEAT, DFEAT);

  // ---- GEMM5: R5 = relu(BN5(R4) @ Wp2 + bp2), stats->BN6 ----
  gemm_bf16<true, true, false><<<ggrid, 256, 0, stream>>>(buf1, DFEAT, BT, DFEAT, biasx, nullptr, buf0, DFEAT, DFEAT, st4);

  // ---- gather (BN6 inline) + tail ----
  gather_kernel<<<64, DFEAT, 0, stream>>>(mask, buf0, st4, bng_g + 6 * DFEAT, bng_b + 6 * DFEAT, invN, flat);
  cat_gemm_kernel<<<dim3(12, 4), 1024, 0, stream>>>(flat, w_cat, b_cat, catrelu);
  bnstats_kernel<<<12, 64, 0, stream>>>(catrelu, Hsent, bn_g, bn_b, aff64);
  final_kernel<<<64, 256, 0, stream>>>(Hsent, catrelu, aff64, w_out, b_out, out);
}